// Round 12
// baseline (169.558 us; speedup 1.0000x reference)
//
#include <hip/hip_runtime.h>
#include <stdint.h>

#define B_ROWS 4096
#define L_FEAT 256
#define VOCAB  8192
#define FRAG   1024             // one MFMA operand fragment: 32 rows x 64 elems
#define KCHUNKS (VOCAB / 64)    // 128 fragments along K per 32-row group
#define GBYTES  (KCHUNKS * FRAG)  // 128 KB per 32-row group
#define NSTEP  128              // K steps of 64 elems

typedef __attribute__((ext_vector_type(4)))  int   intx4;
typedef __attribute__((ext_vector_type(8)))  int   intx8;
typedef __attribute__((ext_vector_type(4)))  float floatx4;
typedef __attribute__((ext_vector_type(16))) float floatx16;

// fp4 operand: HW reads only v[0:3] of the 8-reg A/B field (FMT=4); upper
// half undef (verified r9-r11: passed, absmax 0).
__device__ __forceinline__ intx8 widen(intx4 v) {
  return __builtin_shufflevector(v, v, 0, 1, 2, 3, -1, -1, -1, -1);
}

__device__ __forceinline__ void async_copy16(const void* gsrc, void* ldst) {
  __builtin_amdgcn_global_load_lds(
      (const __attribute__((address_space(1))) void*)gsrc,
      (__attribute__((address_space(3))) void*)ldst, 16, 0, 0);
}

// ---------------- kernel 1: presence in PANEL (MFMA-fragment) layout ---------
// (verified rounds 10/11) fragment (g,kc) holds rows [32g,32g+32) x k-elems
// [64kc,64kc+64), byte = (g*128+kc)*1024 + ((row&31)+32*half)*16.
__global__ __launch_bounds__(256) void presence_kernel(
    const int* __restrict__ f,
    uint32_t* __restrict__ P,     // fp4 presence, panel layout (16 MB)
    float* __restrict__ sizes) {
  __shared__ uint32_t rw[4][VOCAB / 8];   // 4 x 1024 words = 16 KB
  const int rbase = blockIdx.x * 4;
  const int tid = threadIdx.x;

  uint4* rp4 = (uint4*)&rw[0][0];         // 1024 uint4
  const uint4 z = make_uint4(0u, 0u, 0u, 0u);
  #pragma unroll
  for (int j = 0; j < 4; ++j) rp4[tid + j * 256] = z;
  __syncthreads();

  #pragma unroll
  for (int r = 0; r < 4; ++r) {
    const int v = f[(rbase + r) * L_FEAT + tid];     // coalesced
    atomicOr(&rw[r][v >> 3], 0x2u << ((v & 7) * 4)); // fp4 nibble 1.0; dups ok
  }
  __syncthreads();

  // panel write: 1024 chunks of 16B; chunk c -> kc=c>>3, half=(c>>2)&1, ro=c&3
  const int g = blockIdx.x >> 3;
  const int slotBase = (blockIdx.x & 7) * 4;   // row slot within 32-row group
  char* Pg = (char*)P + (size_t)g * GBYTES;
  #pragma unroll
  for (int j = 0; j < 4; ++j) {
    const int c  = tid + j * 256;
    const int kc = c >> 3, h = (c >> 2) & 1, ro = c & 3;
    const uint4 val = *(const uint4*)&rw[ro][kc * 8 + h * 4];
    *(uint4*)(Pg + kc * FRAG + (slotBase + ro + 32 * h) * 16) = val;
  }

  // sizes: wave w popcounts row w
  const int w = tid >> 6, lane = tid & 63;
  const uint4* sp4 = (const uint4*)&rw[w][0];        // 256 uint4
  int cnt = 0;
  #pragma unroll
  for (int q = 0; q < 4; ++q) {
    const uint4 x = sp4[lane + q * 64];
    cnt += __popc(x.x & 0x22222222u) + __popc(x.y & 0x22222222u) +
           __popc(x.z & 0x22222222u) + __popc(x.w & 0x22222222u);
  }
  #pragma unroll
  for (int off = 32; off > 0; off >>= 1) cnt += __shfl_down(cnt, off);
  if (lane == 0) sizes[rbase + w] = (float)cnt;
}

// ---------------- kernel 2: inter = P·P^T (fp4 MX MFMA) + Jaccard + mirror ---
// Round-12: per-wave PRIVATE LDS prefetch ring, ZERO barriers.
//   r10/r11 evidence: register rings get collapsed by the allocator (VGPR 88/
//   116 < ring+acc requirement) -> effective depth 1 -> latency-bound 94 us.
//   global_load_lds gives depth without VGPRs; private slots per wave remove
//   the s_barrier rendezvous (the 2x overhead of r0-r9).
//   * ring: 3 slots x 4 KB per wave (48 KB/block -> 3 blocks/CU, 528 blocks
//     all resident, no tail).
//   * per step: issue STAGE(i+2) (4 gload_lds) -> s_waitcnt vmcnt(8) (own
//     stage(i) landed; stage(i+1)+(i+2) stay in flight; NEVER 0) -> lane-
//     linear ds_read_b128 x4 -> 4 MFMA. Slot safety is in-order wave
//     execution: stage(i+2) writes the slot read at i-1, whose ds_reads were
//     lgkm-waited before i-1's MFMAs (which precede this stage in issue
//     order). No cross-wave hazard exists.
//   * supertile decode + XCD swizzle (r11, FETCH 84->57 MB) kept.
__global__ __launch_bounds__(256, 3) void gemm_kernel(
    const unsigned char* __restrict__ P,
    const float* __restrict__ sizes,
    float* __restrict__ out) {
  // XCD swizzle (528 = 8*66 -> bijective)
  int bid = blockIdx.x;
  bid = (bid & 7) * 66 + (bid >> 3);
  // supertile-triangle decode: 8x8 supertiles of 4x4 blocks, bx >= by
  int b = bid, sy = 0, rem = 122;               // 10 + 16*7
  while (b >= rem) { b -= rem; ++sy; rem -= 16; }
  int by, bx;
  if (b < 10) {                                 // diagonal supertile interior
    int ly = 0, r2 = 4;
    while (b >= r2) { b -= r2; ++ly; --r2; }
    by = sy * 4 + ly; bx = sy * 4 + ly + b;
  } else {
    const int t = b - 10;
    const int sx = sy + 1 + (t >> 4);
    const int l = t & 15;
    by = sy * 4 + (l >> 2); bx = sx * 4 + (l & 3);
  }

  __shared__ __align__(16) unsigned char lds[4][3][4096];  // 48 KB

  const int tid  = threadIdx.x;
  const int wave = tid >> 6, lane = tid & 63;
  const int wm = wave >> 1, wn = wave & 1;   // 2x2 wave grid, each wave 64x64
  const int r31 = lane & 31, khalf = lane >> 5;

  const int iB = by * 128 + wm * 64;   // this wave's output rows
  const int jB = bx * 128 + wn * 64;   // this wave's output cols

  // panel fragment base pointers (global src is per-lane; LDS dst uniform)
  const unsigned char* pA0 = P + (size_t)(by * 4 + wm * 2 + 0) * GBYTES + lane * 16;
  const unsigned char* pA1 = P + (size_t)(by * 4 + wm * 2 + 1) * GBYTES + lane * 16;
  const unsigned char* pB0 = P + (size_t)(bx * 4 + wn * 2 + 0) * GBYTES + lane * 16;
  const unsigned char* pB1 = P + (size_t)(bx * 4 + wn * 2 + 1) * GBYTES + lane * 16;

  unsigned char* myLds = &lds[wave][0][0];   // wave-private 12 KB, 3 slots

  floatx16 acc[2][2];
  #pragma unroll
  for (int ai = 0; ai < 2; ++ai)
    #pragma unroll
    for (int ci = 0; ci < 2; ++ci)
      #pragma unroll
      for (int e = 0; e < 16; ++e) acc[ai][ci][e] = 0.f;

  #define STAGE(slot, koff)                                                   \
    {                                                                         \
      async_copy16(pA0 + (koff), myLds + (slot) * 4096 + 0);                  \
      async_copy16(pA1 + (koff), myLds + (slot) * 4096 + 1024);               \
      async_copy16(pB0 + (koff), myLds + (slot) * 4096 + 2048);               \
      async_copy16(pB1 + (koff), myLds + (slot) * 4096 + 3072);               \
    }

  STAGE(0, 0);              // prologue: depth-2 prefetch (8 vm-ops, no wait)
  STAGE(1, FRAG);

  int cur = 0, pre = 2;
  for (int i = 0; i < NSTEP; ++i) {
    // prefetch step i+2 into the slot read at step i-1 (wraps harmlessly)
    STAGE(pre, (size_t)(((i + 2) & (NSTEP - 1))) * FRAG);

    // own stage(i) landed; 8 newer ops stay in flight (never drains to 0)
    asm volatile("s_waitcnt vmcnt(8)" ::: "memory");

    const unsigned char* s = myLds + cur * 4096 + lane * 16;
    const intx4 A4_0 = *(const intx4*)(s);          // lane-linear: conflict-free
    const intx4 A4_1 = *(const intx4*)(s + 1024);
    const intx4 B4_0 = *(const intx4*)(s + 2048);
    const intx4 B4_1 = *(const intx4*)(s + 3072);
    const intx8 A0 = widen(A4_0), A1 = widen(A4_1);
    const intx8 B0 = widen(B4_0), B1 = widen(B4_1);

    __builtin_amdgcn_s_setprio(1);
    acc[0][0] = __builtin_amdgcn_mfma_scale_f32_32x32x64_f8f6f4(
        A0, B0, acc[0][0], 4, 4, 0, 127, 0, 127);
    acc[0][1] = __builtin_amdgcn_mfma_scale_f32_32x32x64_f8f6f4(
        A0, B1, acc[0][1], 4, 4, 0, 127, 0, 127);
    acc[1][0] = __builtin_amdgcn_mfma_scale_f32_32x32x64_f8f6f4(
        A1, B0, acc[1][0], 4, 4, 0, 127, 0, 127);
    acc[1][1] = __builtin_amdgcn_mfma_scale_f32_32x32x64_f8f6f4(
        A1, B1, acc[1][1], 4, 4, 0, 127, 0, 127);
    __builtin_amdgcn_s_setprio(0);

    cur = (cur == 2) ? 0 : cur + 1;
    pre = (pre == 2) ? 0 : pre + 1;
  }

  // epilogue (verified rounds 5-11): sim = -inter/(|A_i|+|A_j|-inter) + mirror.
  // 32x32 C layout: col = lane&31, row = (reg&3) + 8*(reg>>2) + 4*(lane>>5).
  #pragma unroll
  for (int tm = 0; tm < 2; ++tm) {
    const int rowb = iB + tm * 32 + 4 * khalf;
    #pragma unroll
    for (int tn = 0; tn < 2; ++tn) {
      const int colb = jB + tn * 32 + r31;
      const float sj = sizes[colb];
      #pragma unroll
      for (int q = 0; q < 4; ++q) {           // reg quads: rows rq..rq+3
        const int rq = rowb + 8 * q;
        floatx4 tv;
        #pragma unroll
        for (int j = 0; j < 4; ++j) {
          const float inter = acc[tm][tn][4 * q + j];
          const float u = sizes[rq + j] + sj - inter;
          tv[j] = (u != 0.f) ? (-inter / u) : 0.f;
        }
        __builtin_nontemporal_store(tv[0], &out[(size_t)(rq + 0) * B_ROWS + colb]);
        __builtin_nontemporal_store(tv[1], &out[(size_t)(rq + 1) * B_ROWS + colb]);
        __builtin_nontemporal_store(tv[2], &out[(size_t)(rq + 2) * B_ROWS + colb]);
        __builtin_nontemporal_store(tv[3], &out[(size_t)(rq + 3) * B_ROWS + colb]);
        // mirrored: 4 row-values contiguous in the transposed row (16B-aligned)
        __builtin_nontemporal_store(tv, (floatx4*)&out[(size_t)colb * B_ROWS + rq]);
      }
    }
  }
}

// ---------------- launcher ---------------------------------------------------
extern "C" void kernel_launch(void* const* d_in, const int* in_sizes, int n_in,
                              void* d_out, int out_size, void* d_ws, size_t ws_size,
                              hipStream_t stream) {
  const int* features = (const int*)d_in[0];
  float* out = (float*)d_out;
  uint32_t* P = (uint32_t*)d_ws;                    // 16 MB fp4 panel layout
  float* sizes = (float*)((char*)d_ws + (size_t)(B_ROWS / 32) * GBYTES);

  presence_kernel<<<B_ROWS / 4, 256, 0, stream>>>(features, P, sizes);
  gemm_kernel<<<528, 256, 0, stream>>>((const unsigned char*)P, sizes, out);
}